// Round 25
// baseline (371.197 us; speedup 1.0000x reference)
//
#include <hip/hip_runtime.h>

#define NGR 512
#define NPGC 200
#define NNODE 102400
#define NEDGE 819200
#define SEQM 9728   // 19*512
#define CONVM 51712   // 512*101 rows
#define CONVROWS 51840 // padded rows for tgtT
#define XWS 36        // LDS row stride for gather tiles (bank-spread, 16B-aligned)

typedef float f32x4 __attribute__((ext_vector_type(4)));
typedef __bf16 bf16x8 __attribute__((ext_vector_type(8)));

__device__ __forceinline__ ushort f2bf(float f) {
  unsigned u = __float_as_uint(f);
  u += 0x7FFFu + ((u >> 16) & 1u);
  return (ushort)(u >> 16);
}
__device__ __forceinline__ float bf2f(ushort h) {
  return __uint_as_float(((unsigned)h) << 16);
}
__device__ __forceinline__ void split1(float v, ushort& h, ushort& l) {
  h = f2bf(v);
  l = f2bf(v - bf2f(h));
}

// ---------------- bitonic sort of 256 u64 keys in LDS (any blockDim >= 256) ----------------
__device__ __forceinline__ void bitonic256(unsigned long long* keys, int tid) {
  for (int k = 2; k <= 256; k <<= 1)
    for (int j = k >> 1; j > 0; j >>= 1) {
      __syncthreads();
      if (tid < 256) {
        int ixj = tid ^ j;
        if (ixj > tid) {
          unsigned long long a = keys[tid], b = keys[ixj];
          bool up = ((tid & k) == 0);
          if ((a > b) == up) { keys[tid] = b; keys[ixj] = a; }
        }
      }
    }
  __syncthreads();
}

__device__ __forceinline__ unsigned long long score_key(float sc, int idx) {
  unsigned u = __float_as_uint(sc);
  unsigned m = (u & 0x80000000u) ? ~u : (u | 0x80000000u);
  return (((unsigned long long)(~m)) << 32) | (unsigned)idx;
}

// ---------------- setup: weight transposes (all fp32) ----------------
__global__ void k_setup(const float* __restrict__ w2rel, const float* __restrict__ w2root,
                        const float* __restrict__ b2,
                        const float* __restrict__ wif, const float* __restrict__ wib,
                        const float* __restrict__ bif, const float* __restrict__ bib,
                        const float* __restrict__ whf, const float* __restrict__ whb,
                        const float* __restrict__ d1w, const float* __restrict__ d1b,
                        const float* __restrict__ cw,
                        float* __restrict__ w2t, float* __restrict__ bias2,
                        float* __restrict__ wift, float* __restrict__ biasif,
                        float* __restrict__ whht, float* __restrict__ d1wt,
                        float* __restrict__ biasd1, float* __restrict__ catb,
                        float* __restrict__ Btw)
{
  const long long T1=32768, T2=256, T3=98304, T4=768, T6=86400, T7=622592, T8=128, T9=24576, TB=49152;
  long long total = T1+T2+T3+T4+T6+T7+T8+T9+TB;
  for (long long i = (long long)blockIdx.x*blockDim.x + threadIdx.x; i < total;
       i += (long long)gridDim.x*blockDim.x) {
    long long r = i;
    if (r < T1) { int o=(int)(r>>7), k=(int)(r&127);
      w2t[r] = (o<128)? w2rel[k*128+o] : w2root[k*128+(o-128)]; continue; } r -= T1;
    if (r < T2) { bias2[r] = (r<128)? 0.f : b2[r-128]; continue; } r -= T2;
    if (r < T3) { int o=(int)(r>>7), k=(int)(r&127);
      wift[r] = (o<360)? wif[o*128+k] : ((o<720)? wib[(o-360)*128+k] : 0.f); continue; } r -= T3;
    if (r < T4) { biasif[r] = (r<360)? bif[r] : ((r<720)? bib[r-360] : 0.f); continue; } r -= T4;
    if (r < T6) { int d=(int)(r/43200); int rr=(int)(r%43200); int k=rr/360, o=rr%360;
      whht[r] = d? whb[o*120+k] : whf[o*120+k]; continue; } r -= T6;
    if (r < T7) { int o=(int)(r/4864), k=(int)(r%4864);
      d1wt[r] = (o<102 && k<4816)? d1w[(size_t)k*102+o] : 0.f; continue; } r -= T7;
    if (r < T8) { biasd1[r] = (r<102)? d1b[r] : 0.f; continue; } r -= T8;
    if (r < T9) { int b=(int)(r/48); int c = 4816 + (int)(r%48); catb[(size_t)b*4864+c] = 0.f; continue; } r -= T9;
    { // Btw[o][s*128+ci] = cw[o][ci][s], zero-padded ci>=84
      int o=(int)(r/384), c=(int)(r%384); int s=c>>7, ci=c&127;
      Btw[r] = (ci<84)? cw[o*252 + ci*3 + s] : 0.f; }
  }
}

// wave-scan based exclusive scan of cnt[0..199] into off[0..200]; 2 barriers
__device__ __forceinline__ void scan200(const int* cnt, int* off, int* wsum4, int tid) {
  int v = 0, lane = tid & 63, wv = tid >> 6;
  if (tid < 256) {
    v = (tid < 200) ? cnt[tid] : 0;
    #pragma unroll
    for (int d = 1; d < 64; d <<= 1) {
      int t = __shfl_up(v, d);
      if (lane >= d) v += t;
    }
    if (lane == 63) wsum4[wv] = v;
  }
  __syncthreads();
  if (tid < 256) {
    int add = 0;
    #pragma unroll
    for (int u = 0; u < 3; ++u) if (u < wv) add += wsum4[u];
    if (tid < 200) off[tid+1] = v + add;
    if (tid == 0) off[0] = 0;
  }
  __syncthreads();
}

// gather sum over CSR in-edges, 4 features at once (float4, stride-XWS rows), 2-edge unroll
__device__ __forceinline__ float4 csr_gather4(const ushort* eidx, const float* xw,
                                              int o0, int o1, int h4) {
  float ax0=0.f, ay0=0.f, az0=0.f, aw0=0.f;
  float ax1=0.f, ay1=0.f, az1=0.f, aw1=0.f;
  int j = o0;
  for (; j + 2 <= o1; j += 2) {
    int s0 = eidx[j], s1 = eidx[j+1];
    float4 v0 = *reinterpret_cast<const float4*>(&xw[s0*XWS + h4]);
    float4 v1 = *reinterpret_cast<const float4*>(&xw[s1*XWS + h4]);
    ax0 += v0.x; ay0 += v0.y; az0 += v0.z; aw0 += v0.w;
    ax1 += v1.x; ay1 += v1.y; az1 += v1.z; aw1 += v1.w;
  }
  if (j < o1) {
    float4 v = *reinterpret_cast<const float4*>(&xw[(int)eidx[j]*XWS + h4]);
    ax0 += v.x; ay0 += v.y; az0 += v.z; aw0 += v.w;
  }
  return make_float4(ax0+ax1, ay0+ay1, az0+az1, aw0+aw1);
}

// ---------------- fused layer-1 GraphConv (single float4 gather) + TopK(160) + readout ----------------
__global__ __launch_bounds__(512, 4) void k_g1(
    const float* __restrict__ x, const int* __restrict__ ei,
    const float* __restrict__ w1rel, const float* __restrict__ w1root,
    const float* __restrict__ b1, const float* __restrict__ p1,
    float* __restrict__ hin, unsigned char* __restrict__ m1,
    float* __restrict__ tvg, float* __restrict__ x1)
{
  int g = blockIdx.x, tid = threadIdx.x;
  __shared__ float xs[800];
  __shared__ ushort eloc[1600];     // s | d<<8
  __shared__ ushort eidx[1600];     // src local, grouped by dst
  __shared__ int cnt[200], off[201], wsum4[4];
  __shared__ float wrelF[512], wrootF[512], bF[128], pF[128];
  __shared__ float xw[200*XWS], sacc[200];
  __shared__ unsigned long long keys[256];
  __shared__ unsigned char msk[200];
  __shared__ float tv[200];
  __shared__ float nrm;

  for (int i = tid; i < 800; i += 512) xs[i] = x[g*800 + i];
  for (int e = tid; e < 1600; e += 512) {
    int s = ei[g*1600 + e] - g*200;
    int d = ei[NEDGE + g*1600 + e] - g*200;
    eloc[e] = (ushort)(s | (d << 8));
  }
  { wrelF[tid & 511] = w1rel[tid & 511]; wrootF[tid & 511] = w1root[tid & 511]; }
  if (tid < 128) { bF[tid] = b1[tid]; pF[tid] = p1[tid]; }
  if (tid < 200) { cnt[tid] = 0; sacc[tid] = 0.f; msk[tid] = 0; }
  if (tid < 64) {
    float a = p1[tid], b = p1[64+tid];
    float pp = a*a + b*b;
    pp += __shfl_xor(pp, 32); pp += __shfl_xor(pp, 16); pp += __shfl_xor(pp, 8);
    pp += __shfl_xor(pp, 4);  pp += __shfl_xor(pp, 2);  pp += __shfl_xor(pp, 1);
    if (tid == 0) nrm = rsqrtf(pp);
  }
  __syncthreads();
  for (int e = tid; e < 1600; e += 512) atomicAdd(&cnt[eloc[e] >> 8], 1);
  __syncthreads();
  scan200(cnt, off, wsum4, tid);
  if (tid < 200) cnt[tid] = 0;
  __syncthreads();
  for (int e = tid; e < 1600; e += 512) {
    int p = eloc[e];
    int d = p >> 8;
    int pos = off[d] + atomicAdd(&cnt[d], 1);
    eidx[pos] = (ushort)(p & 255);
  }
  // ---- single pass: raw v -> hin, scores ----
  for (int hc = 0; hc < 4; ++hc) {
    int h0 = hc*32;
    __syncthreads();
    for (int i = tid; i < 1600; i += 512) {
      int nd = i >> 3, hp = i & 7; int f = hp*4 + h0;
      float4 o;
      o.x = xs[nd*4+0]*wrelF[f]   + xs[nd*4+1]*wrelF[128+f]
          + xs[nd*4+2]*wrelF[256+f] + xs[nd*4+3]*wrelF[384+f];
      o.y = xs[nd*4+0]*wrelF[f+1] + xs[nd*4+1]*wrelF[129+f]
          + xs[nd*4+2]*wrelF[257+f] + xs[nd*4+3]*wrelF[385+f];
      o.z = xs[nd*4+0]*wrelF[f+2] + xs[nd*4+1]*wrelF[130+f]
          + xs[nd*4+2]*wrelF[258+f] + xs[nd*4+3]*wrelF[386+f];
      o.w = xs[nd*4+0]*wrelF[f+3] + xs[nd*4+1]*wrelF[131+f]
          + xs[nd*4+2]*wrelF[259+f] + xs[nd*4+3]*wrelF[387+f];
      *reinterpret_cast<float4*>(&xw[nd*XWS + hp*4]) = o;
    }
    __syncthreads();
    for (int i = tid; i < 1600; i += 512) {
      int nd = i >> 3, hp = i & 7; int h4 = hp*4, f = h4 + h0;
      float4 gv = csr_gather4(eidx, xw, off[nd], off[nd+1], h4);
      float4 v;
      v.x = gv.x + xs[nd*4+0]*wrootF[f]   + xs[nd*4+1]*wrootF[128+f]
          + xs[nd*4+2]*wrootF[256+f] + xs[nd*4+3]*wrootF[384+f] + bF[f];
      v.y = gv.y + xs[nd*4+0]*wrootF[f+1] + xs[nd*4+1]*wrootF[129+f]
          + xs[nd*4+2]*wrootF[257+f] + xs[nd*4+3]*wrootF[385+f] + bF[f+1];
      v.z = gv.z + xs[nd*4+0]*wrootF[f+2] + xs[nd*4+1]*wrootF[130+f]
          + xs[nd*4+2]*wrootF[258+f] + xs[nd*4+3]*wrootF[386+f] + bF[f+2];
      v.w = gv.w + xs[nd*4+0]*wrootF[f+3] + xs[nd*4+1]*wrootF[131+f]
          + xs[nd*4+2]*wrootF[259+f] + xs[nd*4+3]*wrootF[387+f] + bF[f+3];
      v.x = fmaxf(v.x, 0.f); v.y = fmaxf(v.y, 0.f);
      v.z = fmaxf(v.z, 0.f); v.w = fmaxf(v.w, 0.f);
      *reinterpret_cast<float4*>(&hin[((size_t)(g*200+nd))*128 + f]) = v;
      float r = v.x*pF[f] + v.y*pF[f+1] + v.z*pF[f+2] + v.w*pF[f+3];
      r += __shfl_xor(r, 4); r += __shfl_xor(r, 2); r += __shfl_xor(r, 1);
      if ((tid & 7) == 0) sacc[nd] += r;
    }
  }
  __syncthreads();
  if (tid < 256) keys[tid] = (tid < 200) ? score_key(sacc[tid], tid) : ~0ull;
  bitonic256(keys, tid);
  if (tid < 160) msk[(int)(keys[tid] & 0xFFFFFFFFu)] = 1;
  if (tid < 200) tv[tid] = tanhf(sacc[tid]*nrm);
  __syncthreads();
  if (tid < 200) { m1[g*200+tid] = msk[tid]; tvg[g*200+tid] = tv[tid]; }
  // ---- pass 2: read-only masked readout (gate applied in-register) ----
  int fp = tid & 63, wv = tid >> 6;
  float2 mx = make_float2(-1e30f, -1e30f), sm = make_float2(0.f, 0.f);
  for (int nd = wv; nd < 200; nd += 8) {
    if (!msk[nd]) continue;
    float2 v = *reinterpret_cast<const float2*>(&hin[((size_t)(g*200+nd))*128 + fp*2]);
    float t = tv[nd];
    v.x *= t; v.y *= t;
    mx.x = fmaxf(mx.x, v.x); mx.y = fmaxf(mx.y, v.y);
    sm.x += v.x; sm.y += v.y;
  }
  float2* redm = reinterpret_cast<float2*>(xw);          // 512 float2
  float2* reds = reinterpret_cast<float2*>(xw + 1024);   // 512 float2
  redm[fp*8 + wv] = mx;
  reds[fp*8 + wv] = sm;
  __syncthreads();
  if (tid < 64) {
    float2 m2 = make_float2(-1e30f, -1e30f), s2 = make_float2(0.f, 0.f);
    #pragma unroll
    for (int w = 0; w < 8; ++w) {
      float2 a = redm[tid*8+w], b = reds[tid*8+w];
      m2.x = fmaxf(m2.x, a.x); m2.y = fmaxf(m2.y, a.y);
      s2.x += b.x; s2.y += b.y;
    }
    x1[g*256 + tid*2]       = m2.x;
    x1[g*256 + tid*2 + 1]   = m2.y;
    x1[g*256 + 128 + tid*2]     = s2.x * (1.f/160.f);
    x1[g*256 + 128 + tid*2 + 1] = s2.y * (1.f/160.f);
  }
}

// ---------------- precise fp32 GEMM via split-bf16 3-pass MFMA, BK=32 ----------------
// LDS 24KB -> 6 blocks/CU; nk=K/32 iterations for latency overlap.
// Work remap: XCD-grouped (requires gridDim.x*gridDim.y % 8 == 0).
// CONV3: A is tgtT[rows][128], K=384 = 3 segments of 128; segment s reads A row (m+s).
// GATE:  A row m scaled by tvg[m] (fp32, before split) during staging.
template<int RELU, int CONV3, int GATE>
__global__ __launch_bounds__(256, 6) void k_gemm32(
    const float* __restrict__ A, const float* __restrict__ Bt,
    const float* __restrict__ bias, const float* __restrict__ tvg,
    float* __restrict__ C, int M, int K, int ldc)
{
  __shared__ ushort Ah[128*32], Al[128*32];   // 8KB each
  __shared__ ushort Bh[64*32],  Bl[64*32];    // 4KB each
  const int tid = threadIdx.x;
  const int GN = gridDim.x;
  const int nwg = GN * gridDim.y;
  const int lin = blockIdx.y*GN + blockIdx.x;
  const int chunk = nwg >> 3;
  const int w = (lin & 7)*chunk + (lin >> 3);   // bijective when nwg%8==0
  const int gm = w / GN, gn = w % GN, gz = blockIdx.z;
  const int lane = tid & 63, wid = tid >> 6;
  const int wm = wid >> 1, wn = wid & 1;
  const int lr = lane & 15, lk = lane >> 4;
  f32x4 acc[4][2] = {};
  const int nk_tot = K >> 5;
  const int per = nk_tot / gridDim.z;
  const int kc0 = gz*per, kc1 = kc0 + per;
  for (int kc = kc0; kc < kc1; ++kc) {
    for (int i = tid; i < 1024; i += 256) {
      int row = i >> 3, c4 = i & 7;
      const float* ap;
      if (CONV3) {
        int kb = kc*32 + c4*4;          // 0..383, 4-float group never crosses seg boundary
        int seg = kb >> 7, col = kb & 127;
        ap = A + ((size_t)(gm*128 + row + seg))*128 + col;
      } else {
        ap = A + (size_t)(gm*128+row)*K + kc*32 + c4*4;
      }
      float4 v = *reinterpret_cast<const float4*>(ap);
      if (GATE) {
        float t = tvg[gm*128 + row];
        v.x *= t; v.y *= t; v.z *= t; v.w *= t;
      }
      ushort4 h, l;
      split1(v.x, h.x, l.x); split1(v.y, h.y, l.y);
      split1(v.z, h.z, l.z); split1(v.w, h.w, l.w);
      int off = (row*64 + c4*8) ^ ((row & 7) << 4);
      *reinterpret_cast<ushort4*>(reinterpret_cast<char*>(Ah) + off) = h;
      *reinterpret_cast<ushort4*>(reinterpret_cast<char*>(Al) + off) = l;
    }
    for (int i = tid; i < 512; i += 256) {
      int row = i >> 3, c4 = i & 7;
      const float4 v = *reinterpret_cast<const float4*>(Bt + (size_t)(gn*64+row)*K + kc*32 + c4*4);
      ushort4 h, l;
      split1(v.x, h.x, l.x); split1(v.y, h.y, l.y);
      split1(v.z, h.z, l.z); split1(v.w, h.w, l.w);
      int off = (row*64 + c4*8) ^ ((row & 7) << 4);
      *reinterpret_cast<ushort4*>(reinterpret_cast<char*>(Bh) + off) = h;
      *reinterpret_cast<ushort4*>(reinterpret_cast<char*>(Bl) + off) = l;
    }
    __syncthreads();
    {
      int kb = lk*16;   // byte offset of this lane's 8-bf16 k-slice
      bf16x8 ah[4], al[4], bh[2], bl[2];
      #pragma unroll
      for (int mf = 0; mf < 4; ++mf) {
        int row = wm*64 + mf*16 + lr;
        int off = (row*64 + kb) ^ ((row & 7) << 4);
        ah[mf] = *reinterpret_cast<const bf16x8*>(reinterpret_cast<const char*>(Ah) + off);
        al[mf] = *reinterpret_cast<const bf16x8*>(reinterpret_cast<const char*>(Al) + off);
      }
      #pragma unroll
      for (int nf = 0; nf < 2; ++nf) {
        int row = wn*32 + nf*16 + lr;
        int off = (row*64 + kb) ^ ((row & 7) << 4);
        bh[nf] = *reinterpret_cast<const bf16x8*>(reinterpret_cast<const char*>(Bh) + off);
        bl[nf] = *reinterpret_cast<const bf16x8*>(reinterpret_cast<const char*>(Bl) + off);
      }
      #pragma unroll
      for (int mf = 0; mf < 4; ++mf)
        #pragma unroll
        for (int nf = 0; nf < 2; ++nf) {
          acc[mf][nf] = __builtin_amdgcn_mfma_f32_16x16x32_bf16(ah[mf], bh[nf], acc[mf][nf], 0, 0, 0);
          acc[mf][nf] = __builtin_amdgcn_mfma_f32_16x16x32_bf16(ah[mf], bl[nf], acc[mf][nf], 0, 0, 0);
          acc[mf][nf] = __builtin_amdgcn_mfma_f32_16x16x32_bf16(al[mf], bh[nf], acc[mf][nf], 0, 0, 0);
        }
    }
    __syncthreads();
  }
  float* Cz = C + (size_t)gz*M*ldc;
  #pragma unroll
  for (int mf = 0; mf < 4; ++mf)
    #pragma unroll
    for (int nf = 0; nf < 2; ++nf)
      #pragma unroll
      for (int j = 0; j < 4; ++j) {
        int m = gm*128 + wm*64 + mf*16 + (lane>>4)*4 + j;
        int n = gn*64 + wn*32 + nf*16 + (lane&15);
        float v = acc[mf][nf][j] + ((gz == 0) ? bias[n] : 0.f);
        if (RELU) v = fmaxf(v, 0.f);
        Cz[(size_t)m*ldc + n] = v;
      }
}

// ---------------- fused layer-2 GraphConv (single masked float4 gather) + TopK(128) + readout ----------------
__global__ __launch_bounds__(512, 4) void k_g2(
    const int* __restrict__ ei, const unsigned char* __restrict__ m1,
    const float* __restrict__ xw2, const float* __restrict__ p2,
    const float* __restrict__ x1, float* __restrict__ vbuf,
    float* __restrict__ catb)
{
  int g = blockIdx.x, tid = threadIdx.x;
  __shared__ unsigned char mk[200], mk2[200];
  __shared__ ushort eloc[1600], eidx[1600];
  __shared__ int cnt[200], off[201], wsum4[4];
  __shared__ float xw[200*XWS], sacc[200], pF[128];
  __shared__ unsigned long long keys[256];
  __shared__ float tv[200];
  __shared__ float nrm;
  if (tid < 200) { mk[tid] = m1[g*200+tid]; sacc[tid] = 0.f; mk2[tid] = 0; cnt[tid] = 0; }
  if (tid < 128) pF[tid] = p2[tid];
  for (int e = tid; e < 1600; e += 512) {
    int s = ei[g*1600 + e] - g*200;
    int d = ei[NEDGE + g*1600 + e] - g*200;
    eloc[e] = (ushort)(s | (d << 8));
  }
  if (tid < 64) {
    float a = p2[tid], b = p2[64+tid];
    float pp = a*a + b*b;
    pp += __shfl_xor(pp, 32); pp += __shfl_xor(pp, 16); pp += __shfl_xor(pp, 8);
    pp += __shfl_xor(pp, 4);  pp += __shfl_xor(pp, 2);  pp += __shfl_xor(pp, 1);
    if (tid == 0) nrm = rsqrtf(pp);
  }
  __syncthreads();
  for (int e = tid; e < 1600; e += 512) {
    int p = eloc[e];
    if (mk[p & 255] && mk[p >> 8]) atomicAdd(&cnt[p >> 8], 1);
  }
  __syncthreads();
  scan200(cnt, off, wsum4, tid);
  if (tid < 200) cnt[tid] = 0;
  __syncthreads();
  for (int e = tid; e < 1600; e += 512) {
    int p = eloc[e];
    int s = p & 255, d = p >> 8;
    if (mk[s] && mk[d]) {
      int pos = off[d] + atomicAdd(&cnt[d], 1);
      eidx[pos] = (ushort)s;
    }
  }
  // ---- single pass: v -> vbuf for m1 nodes, scores ----
  for (int hc = 0; hc < 4; ++hc) {
    int h0 = hc*32;
    __syncthreads();
    for (int i4 = tid; i4 < 1600; i4 += 512) {
      int nd = i4 >> 3, c4 = i4 & 7;
      const float4 v = *reinterpret_cast<const float4*>(xw2 + ((size_t)(g*200+nd))*256 + h0 + c4*4);
      *reinterpret_cast<float4*>(&xw[nd*XWS + c4*4]) = v;
    }
    __syncthreads();
    for (int i = tid; i < 1600; i += 512) {
      int nd = i >> 3, hp = i & 7; int h4 = hp*4, f = h0 + h4;
      if (!mk[nd]) continue;
      float4 gv = csr_gather4(eidx, xw, off[nd], off[nd+1], h4);
      float4 rt = *reinterpret_cast<const float4*>(&xw2[((size_t)(g*200+nd))*256 + 128 + f]);
      float4 v;
      v.x = fmaxf(gv.x + rt.x, 0.f);
      v.y = fmaxf(gv.y + rt.y, 0.f);
      v.z = fmaxf(gv.z + rt.z, 0.f);
      v.w = fmaxf(gv.w + rt.w, 0.f);
      *reinterpret_cast<float4*>(&vbuf[((size_t)(g*200+nd))*128 + f]) = v;
      float r = v.x*pF[f] + v.y*pF[f+1] + v.z*pF[f+2] + v.w*pF[f+3];
      r += __shfl_xor(r, 4); r += __shfl_xor(r, 2); r += __shfl_xor(r, 1);
      if ((tid & 7) == 0) sacc[nd] += r;
    }
  }
  __syncthreads();
  if (tid < 256) {
    unsigned long long kk;
    if (tid < 200) {
      float sc = mk[tid] ? sacc[tid] : -__builtin_inff();
      kk = score_key(sc, tid);
    } else kk = ~0ull;
    keys[tid] = kk;
  }
  bitonic256(keys, tid);
  if (tid < 128) mk2[(int)(keys[tid] & 0xFFFFFFFFu)] = 1;
  if (tid < 200) tv[tid] = tanhf(sacc[tid]*nrm);
  __syncthreads();
  // ---- pass 2: masked re-read + readout ----
  int fp = tid & 63, wv = tid >> 6;
  float2 mx = make_float2(-1e30f, -1e30f), sm = make_float2(0.f, 0.f);
  for (int nd = wv; nd < 200; nd += 8) {
    if (!mk2[nd]) continue;
    float2 v = *reinterpret_cast<const float2*>(&vbuf[((size_t)(g*200+nd))*128 + fp*2]);
    float t = tv[nd];
    v.x *= t; v.y *= t;
    mx.x = fmaxf(mx.x, v.x); mx.y = fmaxf(mx.y, v.y);
    sm.x += v.x; sm.y += v.y;
  }
  float2* redm = reinterpret_cast<float2*>(xw);
  float2* reds = reinterpret_cast<float2*>(xw + 1024);
  redm[fp*8 + wv] = mx;
  reds[fp*8 + wv] = sm;
  __syncthreads();
  if (tid < 64) {
    float2 m2 = make_float2(-1e30f, -1e30f), s2 = make_float2(0.f, 0.f);
    #pragma unroll
    for (int w = 0; w < 8; ++w) {
      float2 a = redm[tid*8+w], b = reds[tid*8+w];
      m2.x = fmaxf(m2.x, a.x); m2.y = fmaxf(m2.y, a.y);
      s2.x += b.x; s2.y += b.y;
    }
    catb[(size_t)g*4864 + tid*2]           = x1[g*256 + tid*2] + m2.x;
    catb[(size_t)g*4864 + tid*2 + 1]       = x1[g*256 + tid*2 + 1] + m2.y;
    catb[(size_t)g*4864 + 128 + tid*2]     = x1[g*256 + 128 + tid*2] + s2.x*(1.f/128.f);
    catb[(size_t)g*4864 + 128 + tid*2 + 1] = x1[g*256 + 128 + tid*2 + 1] + s2.y*(1.f/128.f);
  }
}

// ---------------- transpose tgt[b][ci][t] -> tgtT[(b*101+t)][128] (ci-major, zero-padded) ----------------
__global__ __launch_bounds__(256) void k_transp(
    const float* __restrict__ tgt, float* __restrict__ tgtT)
{
  int b = blockIdx.x, tid = threadIdx.x;
  __shared__ float tgs[8484];
  for (int i = tid; i < 8484; i += 256) tgs[i] = tgt[(size_t)b*8484 + i];
  __syncthreads();
  for (int i = tid; i < 12928; i += 256) {   // 101*128
    int t = i >> 7, ci = i & 127;
    tgtT[((size_t)(b*101 + t))*128 + ci] = (ci < 84) ? tgs[ci*101 + t] : 0.f;
  }
}

// ---------------- avgpool5 over conv output rows: xl[(b*101+t)][o] -> xp[(tp*512+b)][o] ----------------
__global__ __launch_bounds__(512) void k_avgpool(
    const float* __restrict__ xl, float* __restrict__ xp)
{
  int b = blockIdx.x, tid = threadIdx.x;
  for (int i = tid; i < 2432; i += 512) {    // 19*128
    int tp = i >> 7, o = i & 127;
    int t0 = tp*5;
    float s = 0.f;
    #pragma unroll
    for (int q = 0; q < 5; ++q)
      s += xl[((size_t)(b*101 + t0 + q))*128 + o];
    xp[((size_t)(tp*512 + b))*128 + o] = s*0.2f;
  }
}

// ---------------- bidirectional GRU: 768 threads = 8 k-groups x 90 col-groups (4 cols each) ----
// R24 model: GRU is VMEM-ISSUE bound (24 waves x 60 scalar weight loads/step = 1440 instrs/CU/step
// ~ 5800 cyc ~ measured 67us). Fix: thread owns 4 ADJACENT columns x 15 contiguous k ->
// weight stream = 15 x dwordx4 (still wave-coalesced in the [k][360] layout) = 4x fewer issues.
// h-values become wave-broadcast scalars; partials ps[2][8][360] reduced by gate threads.
__global__ __launch_bounds__(768, 3) void k_gru(
    const float* __restrict__ whht, const float* __restrict__ bhf,
    const float* __restrict__ bhb, const float* __restrict__ gi,
    float* __restrict__ catb)
{
  int blk = blockIdx.x;            // 512 blocks
  int dir = blk & 1, grp = blk >> 1;   // rows grp*2, grp*2+1
  const float* wh = whht + dir*43200;  // [k][360]
  const float* bhh = dir ? bhb : bhf;
  __shared__ float h_l[240];       // [2][120]
  __shared__ float ps[2][8][360];  // [row][kgroup][c] partials
  __shared__ float bhs[360];
  int tid = threadIdx.x;
  int t  = (tid < 720) ? tid : 719;
  int kg = t / 90;              // k-group 0..7 (15 k each)
  int cg = t % 90;              // column group (cols cg*4 .. cg*4+3)
  const float* wbase = wh + (kg*15)*360 + cg*4;
  if (tid < 360) bhs[tid] = bhh[tid];
  if (tid < 240) h_l[tid] = 0.f;
  __syncthreads();
  for (int step = 0; step < 19; ++step) {
    int time = dir ? (18 - step) : step;
    {
      float4 a0 = make_float4(0.f,0.f,0.f,0.f), a1 = make_float4(0.f,0.f,0.f,0.f);
      #pragma unroll
      for (int j = 0; j < 15; ++j) {
        float4 w = *reinterpret_cast<const float4*>(wbase + j*360);
        float h0 = h_l[kg*15 + j];
        float h1 = h_l[120 + kg*15 + j];
        a0.x += h0*w.x; a0.y += h0*w.y; a0.z += h0*w.z; a0.w += h0*w.w;
        a1.x += h1*w.x; a1.y += h1*w.y; a1.z += h1*w.z; a1.w += h1*w.w;
      }
      if (tid < 720) {
        *reinterpret_cast<float4*>(&ps[0][kg][cg*4]) = a0;
        *reinterpret_cast<float4*>(&ps[1][kg][cg*4]) = a1;
      }
    }
    __syncthreads();
    if (tid < 240) {
      int b2 = tid >= 120, cc = tid - b2*120;
      size_t row = (size_t)time*512 + grp*2 + b2;
      const float* gir = gi + row*768 + dir*360;
      float hr = 0.f, hz = 0.f, hn = 0.f;
      #pragma unroll
      for (int q = 0; q < 8; ++q) {
        hr += ps[b2][q][cc];
        hz += ps[b2][q][120+cc];
        hn += ps[b2][q][240+cc];
      }
      hr += bhs[cc]; hz += bhs[120+cc]; hn += bhs[240+cc];
      float ir = gir[cc], iz = gir[120+cc], inn = gir[240+cc];
      float r = 1.f/(1.f + expf(-(ir+hr)));
      float z = 1.f/(1.f + expf(-(iz+hz)));
      float n = tanhf(inn + r*hn);
      float hnew = (1.f - z)*n + z*h_l[tid];
      h_l[tid] = hnew;
      catb[((size_t)(grp*2+b2))*4864 + 256 + time*240 + dir*120 + cc] = hnew;
    }
    __syncthreads();
  }
}

// ---------------- final: parallel sum of 19 K-split partials + relu + logits + log_softmax ----------------
__global__ __launch_bounds__(128) void k_final(
    const float* __restrict__ xcp, const float* __restrict__ d3w,
    const float* __restrict__ d3b, float* __restrict__ out)
{
  int row = blockIdx.x;          // 512 blocks, one per output row
  int k = threadIdx.x;           // 128 threads, 102 active
  __shared__ float red[4];
  float l0 = 0.f, l1 = 0.f;
  if (k < 102) {
    float v = 0.f;
    #pragma unroll
    for (int z = 0; z < 19; ++z)
      v += xcp[(size_t)z*65536 + (size_t)row*128 + k];
    v = fmaxf(v, 0.f);
    l0 = v*d3w[k*2+0];
    l1 = v*d3w[k*2+1];
  }
  #pragma unroll
  for (int d = 32; d > 0; d >>= 1) {
    l0 += __shfl_xor(l0, d);
    l1 += __shfl_xor(l1, d);
  }
  int lane = k & 63, wv = k >> 6;
  if (lane == 0) { red[wv*2] = l0; red[wv*2+1] = l1; }
  __syncthreads();
  if (k == 0) {
    float a0 = red[0] + red[2] + d3b[0];
    float a1 = red[1] + red[3] + d3b[1];
    float m = fmaxf(a0, a1);
    float lse = m + logf(expf(a0-m) + expf(a1-m));
    out[row*2+0] = a0 - lse;
    out[row*2+1] = a1 - lse;
  }
}

extern "C" void kernel_launch(void* const* d_in, const int* in_sizes, int n_in,
                              void* d_out, int out_size, void* d_ws, size_t ws_size,
                              hipStream_t stream) {
  (void)in_sizes; (void)n_in; (void)out_size;
  const float* x      = (const float*)d_in[0];
  const int*   ei     = (const int*)d_in[1];
  const float* tgt    = (const float*)d_in[3];
  const float* w1rel  = (const float*)d_in[4];
  const float* w1root = (const float*)d_in[5];
  const float* b1     = (const float*)d_in[6];
  const float* p1     = (const float*)d_in[7];
  const float* w2rel  = (const float*)d_in[8];
  const float* w2root = (const float*)d_in[9];
  const float* b2     = (const float*)d_in[10];
  const float* p2     = (const float*)d_in[11];
  const float* cw     = (const float*)d_in[12];
  const float* cb     = (const float*)d_in[13];
  const float* wif    = (const float*)d_in[14];
  const float* whf    = (const float*)d_in[15];
  const float* bif    = (const float*)d_in[16];
  const float* bhf    = (const float*)d_in[17];
  const float* wib    = (const float*)d_in[18];
  const float* whb    = (const float*)d_in[19];
  const float* bib    = (const float*)d_in[20];
  const float* bhb    = (const float*)d_in[21];
  const float* d1w    = (const float*)d_in[22];
  const float* d1b    = (const float*)d_in[23];
  const float* d3w    = (const float*)d_in[24];
  const float* d3b    = (const float*)d_in[25];
  float* out = (float*)d_out;

  char* ws = (char*)d_ws;
  size_t off = 0;
  auto alloc = [&](size_t bytes) -> char* {
    char* p = ws + off;
    off = (off + bytes + 255) & ~(size_t)255;
    return p;
  };
  float* hin    = (float*)alloc((size_t)NNODE*128*4);     // 52.4MB (also reused as vbuf by k_g2)
  unsigned char* m1b = (unsigned char*)alloc(NNODE);
  float* tvg    = (float*)alloc((size_t)NNODE*4);         // per-node gate
  float* x1     = (float*)alloc((size_t)512*256*4);
  float* w2t    = (float*)alloc((size_t)32768*4);
  float* bias2  = (float*)alloc((size_t)256*4);
  float* xw2    = (float*)alloc((size_t)NNODE*256*4);     // 104.9MB; dead after k_g2 -> reused as tgtT + xl
  float* xp     = (float*)alloc((size_t)SEQM*128*4);      // 5.0MB
  float* wift   = (float*)alloc((size_t)98304*4);
  float* biasif = (float*)alloc((size_t)768*4);
  float* gi     = (float*)alloc((size_t)SEQM*768*4);      // 29.9MB
  float* whht   = (float*)alloc((size_t)86400*4);
  float* catb   = (float*)alloc((size_t)512*4864*4);      // 10.0MB
  float* d1wt   = (float*)alloc((size_t)622592*4);        // 2.5MB
  float* biasd1 = (float*)alloc((size_t)128*4);
  float* xcp    = (float*)alloc((size_t)19*512*128*4);    // 5.0MB
  float* Btw    = (float*)alloc((size_t)128*384*4);       // 0.2MB conv weights [o][3*128]
  if (off > ws_size) return;  // workspace too small; bail (output stays poisoned)

  // aliases into dead xw2 (valid only after k_g2):
  float* tgtT = xw2;                               // CONVROWS x 128 = 26.5MB
  float* xl   = xw2 + (size_t)CONVROWS*128;        // CONVM x 128 = 26.5MB

  k_setup<<<1024, 256, 0, stream>>>(w2rel, w2root, b2, wif, wib, bif, bib,
                                    whf, whb, d1w, d1b, cw,
                                    w2t, bias2, wift, biasif, whht, d1wt, biasd1, catb, Btw);
  k_g1<<<512, 512, 0, stream>>>(x, ei, w1rel, w1root, b1, p1, hin, m1b, tvg, x1);
  k_gemm32<0,0,1><<<dim3(4,800,1), 256, 0, stream>>>(hin, w2t, bias2, tvg, xw2, NNODE, 128, 256);
  k_g2<<<512, 512, 0, stream>>>(ei, m1b, xw2, p2, x1, hin, catb);
  k_transp<<<512, 256, 0, stream>>>(tgt, tgtT);
  k_gemm32<1,1,0><<<dim3(2,404,1), 256, 0, stream>>>(tgtT, Btw, cb, nullptr, xl, CONVM, 384, 128);
  k_avgpool<<<512, 512, 0, stream>>>(xl, xp);
  k_gemm32<0,0,0><<<dim3(12,76,1), 256, 0, stream>>>(xp, wift, biasif, nullptr, gi, SEQM, 128, 768);
  k_gru<<<512, 768, 0, stream>>>(whht, bhf, bhb, gi, catb);
  k_gemm32<0,0,0><<<dim3(2,4,19), 256, 0, stream>>>(catb, d1wt, biasd1, nullptr, xcp, 512, 4864, 128);
  k_final<<<512, 128, 0, stream>>>(xcp, d3w, d3b, out);
}

// Round 27
// 346.272 us; speedup vs baseline: 1.0720x; 1.0720x over previous
//
#include <hip/hip_runtime.h>

#define NGR 512
#define NPGC 200
#define NNODE 102400
#define NEDGE 819200
#define SEQM 9728   // 19*512
#define CONVM 51712   // 512*101 rows
#define CONVROWS 51840 // padded rows for tgtT
#define XWS 36        // LDS row stride for gather tiles (bank-spread, 16B-aligned)

typedef float f32x4 __attribute__((ext_vector_type(4)));
typedef __bf16 bf16x8 __attribute__((ext_vector_type(8)));

__device__ __forceinline__ ushort f2bf(float f) {
  unsigned u = __float_as_uint(f);
  u += 0x7FFFu + ((u >> 16) & 1u);
  return (ushort)(u >> 16);
}
__device__ __forceinline__ float bf2f(ushort h) {
  return __uint_as_float(((unsigned)h) << 16);
}
__device__ __forceinline__ void split1(float v, ushort& h, ushort& l) {
  h = f2bf(v);
  l = f2bf(v - bf2f(h));
}

// ---------------- bitonic sort of 256 u64 keys in LDS (any blockDim >= 256) ----------------
__device__ __forceinline__ void bitonic256(unsigned long long* keys, int tid) {
  for (int k = 2; k <= 256; k <<= 1)
    for (int j = k >> 1; j > 0; j >>= 1) {
      __syncthreads();
      if (tid < 256) {
        int ixj = tid ^ j;
        if (ixj > tid) {
          unsigned long long a = keys[tid], b = keys[ixj];
          bool up = ((tid & k) == 0);
          if ((a > b) == up) { keys[tid] = b; keys[ixj] = a; }
        }
      }
    }
  __syncthreads();
}

__device__ __forceinline__ unsigned long long score_key(float sc, int idx) {
  unsigned u = __float_as_uint(sc);
  unsigned m = (u & 0x80000000u) ? ~u : (u | 0x80000000u);
  return (((unsigned long long)(~m)) << 32) | (unsigned)idx;
}

// ---------------- setup: weight transposes (all fp32) ----------------
__global__ void k_setup(const float* __restrict__ w2rel, const float* __restrict__ w2root,
                        const float* __restrict__ b2,
                        const float* __restrict__ wif, const float* __restrict__ wib,
                        const float* __restrict__ bif, const float* __restrict__ bib,
                        const float* __restrict__ whf, const float* __restrict__ whb,
                        const float* __restrict__ d1w, const float* __restrict__ d1b,
                        const float* __restrict__ cw,
                        float* __restrict__ w2t, float* __restrict__ bias2,
                        float* __restrict__ wift, float* __restrict__ biasif,
                        float* __restrict__ whht, float* __restrict__ d1wt,
                        float* __restrict__ biasd1, float* __restrict__ catb,
                        float* __restrict__ Btw)
{
  const long long T1=32768, T2=256, T3=98304, T4=768, T6=86400, T7=622592, T8=128, T9=24576, TB=49152;
  long long total = T1+T2+T3+T4+T6+T7+T8+T9+TB;
  for (long long i = (long long)blockIdx.x*blockDim.x + threadIdx.x; i < total;
       i += (long long)gridDim.x*blockDim.x) {
    long long r = i;
    if (r < T1) { int o=(int)(r>>7), k=(int)(r&127);
      w2t[r] = (o<128)? w2rel[k*128+o] : w2root[k*128+(o-128)]; continue; } r -= T1;
    if (r < T2) { bias2[r] = (r<128)? 0.f : b2[r-128]; continue; } r -= T2;
    if (r < T3) { int o=(int)(r>>7), k=(int)(r&127);
      wift[r] = (o<360)? wif[o*128+k] : ((o<720)? wib[(o-360)*128+k] : 0.f); continue; } r -= T3;
    if (r < T4) { biasif[r] = (r<360)? bif[r] : ((r<720)? bib[r-360] : 0.f); continue; } r -= T4;
    if (r < T6) { int d=(int)(r/43200); int rr=(int)(r%43200); int k=rr/360, o=rr%360;
      whht[r] = d? whb[o*120+k] : whf[o*120+k]; continue; } r -= T6;
    if (r < T7) { int o=(int)(r/4864), k=(int)(r%4864);
      d1wt[r] = (o<102 && k<4816)? d1w[(size_t)k*102+o] : 0.f; continue; } r -= T7;
    if (r < T8) { biasd1[r] = (r<102)? d1b[r] : 0.f; continue; } r -= T8;
    if (r < T9) { int b=(int)(r/48); int c = 4816 + (int)(r%48); catb[(size_t)b*4864+c] = 0.f; continue; } r -= T9;
    { // Btw[o][s*128+ci] = cw[o][ci][s], zero-padded ci>=84
      int o=(int)(r/384), c=(int)(r%384); int s=c>>7, ci=c&127;
      Btw[r] = (ci<84)? cw[o*252 + ci*3 + s] : 0.f; }
  }
}

// wave-scan based exclusive scan of cnt[0..199] into off[0..200]; 2 barriers
__device__ __forceinline__ void scan200(const int* cnt, int* off, int* wsum4, int tid) {
  int v = 0, lane = tid & 63, wv = tid >> 6;
  if (tid < 256) {
    v = (tid < 200) ? cnt[tid] : 0;
    #pragma unroll
    for (int d = 1; d < 64; d <<= 1) {
      int t = __shfl_up(v, d);
      if (lane >= d) v += t;
    }
    if (lane == 63) wsum4[wv] = v;
  }
  __syncthreads();
  if (tid < 256) {
    int add = 0;
    #pragma unroll
    for (int u = 0; u < 3; ++u) if (u < wv) add += wsum4[u];
    if (tid < 200) off[tid+1] = v + add;
    if (tid == 0) off[0] = 0;
  }
  __syncthreads();
}

// gather sum over CSR in-edges, 4 features at once (float4, stride-XWS rows), 2-edge unroll
__device__ __forceinline__ float4 csr_gather4(const ushort* eidx, const float* xw,
                                              int o0, int o1, int h4) {
  float ax0=0.f, ay0=0.f, az0=0.f, aw0=0.f;
  float ax1=0.f, ay1=0.f, az1=0.f, aw1=0.f;
  int j = o0;
  for (; j + 2 <= o1; j += 2) {
    int s0 = eidx[j], s1 = eidx[j+1];
    float4 v0 = *reinterpret_cast<const float4*>(&xw[s0*XWS + h4]);
    float4 v1 = *reinterpret_cast<const float4*>(&xw[s1*XWS + h4]);
    ax0 += v0.x; ay0 += v0.y; az0 += v0.z; aw0 += v0.w;
    ax1 += v1.x; ay1 += v1.y; az1 += v1.z; aw1 += v1.w;
  }
  if (j < o1) {
    float4 v = *reinterpret_cast<const float4*>(&xw[(int)eidx[j]*XWS + h4]);
    ax0 += v.x; ay0 += v.y; az0 += v.z; aw0 += v.w;
  }
  return make_float4(ax0+ax1, ay0+ay1, az0+az1, aw0+aw1);
}

// ---------------- fused layer-1 GraphConv (single float4 gather) + TopK(160) + readout ----------------
__global__ __launch_bounds__(512, 4) void k_g1(
    const float* __restrict__ x, const int* __restrict__ ei,
    const float* __restrict__ w1rel, const float* __restrict__ w1root,
    const float* __restrict__ b1, const float* __restrict__ p1,
    float* __restrict__ hin, unsigned char* __restrict__ m1,
    float* __restrict__ tvg, float* __restrict__ x1)
{
  int g = blockIdx.x, tid = threadIdx.x;
  __shared__ float xs[800];
  __shared__ ushort eloc[1600];     // s | d<<8
  __shared__ ushort eidx[1600];     // src local, grouped by dst
  __shared__ int cnt[200], off[201], wsum4[4];
  __shared__ float wrelF[512], wrootF[512], bF[128], pF[128];
  __shared__ float xw[200*XWS], sacc[200];
  __shared__ unsigned long long keys[256];
  __shared__ unsigned char msk[200];
  __shared__ float tv[200];
  __shared__ float nrm;

  for (int i = tid; i < 800; i += 512) xs[i] = x[g*800 + i];
  for (int e = tid; e < 1600; e += 512) {
    int s = ei[g*1600 + e] - g*200;
    int d = ei[NEDGE + g*1600 + e] - g*200;
    eloc[e] = (ushort)(s | (d << 8));
  }
  { wrelF[tid & 511] = w1rel[tid & 511]; wrootF[tid & 511] = w1root[tid & 511]; }
  if (tid < 128) { bF[tid] = b1[tid]; pF[tid] = p1[tid]; }
  if (tid < 200) { cnt[tid] = 0; sacc[tid] = 0.f; msk[tid] = 0; }
  if (tid < 64) {
    float a = p1[tid], b = p1[64+tid];
    float pp = a*a + b*b;
    pp += __shfl_xor(pp, 32); pp += __shfl_xor(pp, 16); pp += __shfl_xor(pp, 8);
    pp += __shfl_xor(pp, 4);  pp += __shfl_xor(pp, 2);  pp += __shfl_xor(pp, 1);
    if (tid == 0) nrm = rsqrtf(pp);
  }
  __syncthreads();
  for (int e = tid; e < 1600; e += 512) atomicAdd(&cnt[eloc[e] >> 8], 1);
  __syncthreads();
  scan200(cnt, off, wsum4, tid);
  if (tid < 200) cnt[tid] = 0;
  __syncthreads();
  for (int e = tid; e < 1600; e += 512) {
    int p = eloc[e];
    int d = p >> 8;
    int pos = off[d] + atomicAdd(&cnt[d], 1);
    eidx[pos] = (ushort)(p & 255);
  }
  // ---- single pass: raw v -> hin, scores ----
  for (int hc = 0; hc < 4; ++hc) {
    int h0 = hc*32;
    __syncthreads();
    for (int i = tid; i < 1600; i += 512) {
      int nd = i >> 3, hp = i & 7; int f = hp*4 + h0;
      float4 o;
      o.x = xs[nd*4+0]*wrelF[f]   + xs[nd*4+1]*wrelF[128+f]
          + xs[nd*4+2]*wrelF[256+f] + xs[nd*4+3]*wrelF[384+f];
      o.y = xs[nd*4+0]*wrelF[f+1] + xs[nd*4+1]*wrelF[129+f]
          + xs[nd*4+2]*wrelF[257+f] + xs[nd*4+3]*wrelF[385+f];
      o.z = xs[nd*4+0]*wrelF[f+2] + xs[nd*4+1]*wrelF[130+f]
          + xs[nd*4+2]*wrelF[258+f] + xs[nd*4+3]*wrelF[386+f];
      o.w = xs[nd*4+0]*wrelF[f+3] + xs[nd*4+1]*wrelF[131+f]
          + xs[nd*4+2]*wrelF[259+f] + xs[nd*4+3]*wrelF[387+f];
      *reinterpret_cast<float4*>(&xw[nd*XWS + hp*4]) = o;
    }
    __syncthreads();
    for (int i = tid; i < 1600; i += 512) {
      int nd = i >> 3, hp = i & 7; int h4 = hp*4, f = h4 + h0;
      float4 gv = csr_gather4(eidx, xw, off[nd], off[nd+1], h4);
      float4 v;
      v.x = gv.x + xs[nd*4+0]*wrootF[f]   + xs[nd*4+1]*wrootF[128+f]
          + xs[nd*4+2]*wrootF[256+f] + xs[nd*4+3]*wrootF[384+f] + bF[f];
      v.y = gv.y + xs[nd*4+0]*wrootF[f+1] + xs[nd*4+1]*wrootF[129+f]
          + xs[nd*4+2]*wrootF[257+f] + xs[nd*4+3]*wrootF[385+f] + bF[f+1];
      v.z = gv.z + xs[nd*4+0]*wrootF[f+2] + xs[nd*4+1]*wrootF[130+f]
          + xs[nd*4+2]*wrootF[258+f] + xs[nd*4+3]*wrootF[386+f] + bF[f+2];
      v.w = gv.w + xs[nd*4+0]*wrootF[f+3] + xs[nd*4+1]*wrootF[131+f]
          + xs[nd*4+2]*wrootF[259+f] + xs[nd*4+3]*wrootF[387+f] + bF[f+3];
      v.x = fmaxf(v.x, 0.f); v.y = fmaxf(v.y, 0.f);
      v.z = fmaxf(v.z, 0.f); v.w = fmaxf(v.w, 0.f);
      *reinterpret_cast<float4*>(&hin[((size_t)(g*200+nd))*128 + f]) = v;
      float r = v.x*pF[f] + v.y*pF[f+1] + v.z*pF[f+2] + v.w*pF[f+3];
      r += __shfl_xor(r, 4); r += __shfl_xor(r, 2); r += __shfl_xor(r, 1);
      if ((tid & 7) == 0) sacc[nd] += r;
    }
  }
  __syncthreads();
  if (tid < 256) keys[tid] = (tid < 200) ? score_key(sacc[tid], tid) : ~0ull;
  bitonic256(keys, tid);
  if (tid < 160) msk[(int)(keys[tid] & 0xFFFFFFFFu)] = 1;
  if (tid < 200) tv[tid] = tanhf(sacc[tid]*nrm);
  __syncthreads();
  if (tid < 200) { m1[g*200+tid] = msk[tid]; tvg[g*200+tid] = tv[tid]; }
  // ---- pass 2: read-only masked readout (gate applied in-register) ----
  int fp = tid & 63, wv = tid >> 6;
  float2 mx = make_float2(-1e30f, -1e30f), sm = make_float2(0.f, 0.f);
  for (int nd = wv; nd < 200; nd += 8) {
    if (!msk[nd]) continue;
    float2 v = *reinterpret_cast<const float2*>(&hin[((size_t)(g*200+nd))*128 + fp*2]);
    float t = tv[nd];
    v.x *= t; v.y *= t;
    mx.x = fmaxf(mx.x, v.x); mx.y = fmaxf(mx.y, v.y);
    sm.x += v.x; sm.y += v.y;
  }
  float2* redm = reinterpret_cast<float2*>(xw);          // 512 float2
  float2* reds = reinterpret_cast<float2*>(xw + 1024);   // 512 float2
  redm[fp*8 + wv] = mx;
  reds[fp*8 + wv] = sm;
  __syncthreads();
  if (tid < 64) {
    float2 m2 = make_float2(-1e30f, -1e30f), s2 = make_float2(0.f, 0.f);
    #pragma unroll
    for (int w = 0; w < 8; ++w) {
      float2 a = redm[tid*8+w], b = reds[tid*8+w];
      m2.x = fmaxf(m2.x, a.x); m2.y = fmaxf(m2.y, a.y);
      s2.x += b.x; s2.y += b.y;
    }
    x1[g*256 + tid*2]       = m2.x;
    x1[g*256 + tid*2 + 1]   = m2.y;
    x1[g*256 + 128 + tid*2]     = s2.x * (1.f/160.f);
    x1[g*256 + 128 + tid*2 + 1] = s2.y * (1.f/160.f);
  }
}

// ---------------- precise fp32 GEMM via split-bf16 3-pass MFMA, BK=32 ----------------
// LDS 24KB -> 6 blocks/CU; nk=K/32 iterations for latency overlap.
// Work remap: XCD-grouped (requires gridDim.x*gridDim.y % 8 == 0).
// CONV3: A is tgtT[rows][128], K=384 = 3 segments of 128; segment s reads A row (m+s).
// GATE:  A row m scaled by tvg[m] (fp32, before split) during staging.
template<int RELU, int CONV3, int GATE>
__global__ __launch_bounds__(256, 6) void k_gemm32(
    const float* __restrict__ A, const float* __restrict__ Bt,
    const float* __restrict__ bias, const float* __restrict__ tvg,
    float* __restrict__ C, int M, int K, int ldc)
{
  __shared__ ushort Ah[128*32], Al[128*32];   // 8KB each
  __shared__ ushort Bh[64*32],  Bl[64*32];    // 4KB each
  const int tid = threadIdx.x;
  const int GN = gridDim.x;
  const int nwg = GN * gridDim.y;
  const int lin = blockIdx.y*GN + blockIdx.x;
  const int chunk = nwg >> 3;
  const int w = (lin & 7)*chunk + (lin >> 3);   // bijective when nwg%8==0
  const int gm = w / GN, gn = w % GN, gz = blockIdx.z;
  const int lane = tid & 63, wid = tid >> 6;
  const int wm = wid >> 1, wn = wid & 1;
  const int lr = lane & 15, lk = lane >> 4;
  f32x4 acc[4][2] = {};
  const int nk_tot = K >> 5;
  const int per = nk_tot / gridDim.z;
  const int kc0 = gz*per, kc1 = kc0 + per;
  for (int kc = kc0; kc < kc1; ++kc) {
    for (int i = tid; i < 1024; i += 256) {
      int row = i >> 3, c4 = i & 7;
      const float* ap;
      if (CONV3) {
        int kb = kc*32 + c4*4;          // 0..383, 4-float group never crosses seg boundary
        int seg = kb >> 7, col = kb & 127;
        ap = A + ((size_t)(gm*128 + row + seg))*128 + col;
      } else {
        ap = A + (size_t)(gm*128+row)*K + kc*32 + c4*4;
      }
      float4 v = *reinterpret_cast<const float4*>(ap);
      if (GATE) {
        float t = tvg[gm*128 + row];
        v.x *= t; v.y *= t; v.z *= t; v.w *= t;
      }
      ushort4 h, l;
      split1(v.x, h.x, l.x); split1(v.y, h.y, l.y);
      split1(v.z, h.z, l.z); split1(v.w, h.w, l.w);
      int off = (row*64 + c4*8) ^ ((row & 7) << 4);
      *reinterpret_cast<ushort4*>(reinterpret_cast<char*>(Ah) + off) = h;
      *reinterpret_cast<ushort4*>(reinterpret_cast<char*>(Al) + off) = l;
    }
    for (int i = tid; i < 512; i += 256) {
      int row = i >> 3, c4 = i & 7;
      const float4 v = *reinterpret_cast<const float4*>(Bt + (size_t)(gn*64+row)*K + kc*32 + c4*4);
      ushort4 h, l;
      split1(v.x, h.x, l.x); split1(v.y, h.y, l.y);
      split1(v.z, h.z, l.z); split1(v.w, h.w, l.w);
      int off = (row*64 + c4*8) ^ ((row & 7) << 4);
      *reinterpret_cast<ushort4*>(reinterpret_cast<char*>(Bh) + off) = h;
      *reinterpret_cast<ushort4*>(reinterpret_cast<char*>(Bl) + off) = l;
    }
    __syncthreads();
    {
      int kb = lk*16;   // byte offset of this lane's 8-bf16 k-slice
      bf16x8 ah[4], al[4], bh[2], bl[2];
      #pragma unroll
      for (int mf = 0; mf < 4; ++mf) {
        int row = wm*64 + mf*16 + lr;
        int off = (row*64 + kb) ^ ((row & 7) << 4);
        ah[mf] = *reinterpret_cast<const bf16x8*>(reinterpret_cast<const char*>(Ah) + off);
        al[mf] = *reinterpret_cast<const bf16x8*>(reinterpret_cast<const char*>(Al) + off);
      }
      #pragma unroll
      for (int nf = 0; nf < 2; ++nf) {
        int row = wn*32 + nf*16 + lr;
        int off = (row*64 + kb) ^ ((row & 7) << 4);
        bh[nf] = *reinterpret_cast<const bf16x8*>(reinterpret_cast<const char*>(Bh) + off);
        bl[nf] = *reinterpret_cast<const bf16x8*>(reinterpret_cast<const char*>(Bl) + off);
      }
      #pragma unroll
      for (int mf = 0; mf < 4; ++mf)
        #pragma unroll
        for (int nf = 0; nf < 2; ++nf) {
          acc[mf][nf] = __builtin_amdgcn_mfma_f32_16x16x32_bf16(ah[mf], bh[nf], acc[mf][nf], 0, 0, 0);
          acc[mf][nf] = __builtin_amdgcn_mfma_f32_16x16x32_bf16(ah[mf], bl[nf], acc[mf][nf], 0, 0, 0);
          acc[mf][nf] = __builtin_amdgcn_mfma_f32_16x16x32_bf16(al[mf], bh[nf], acc[mf][nf], 0, 0, 0);
        }
    }
    __syncthreads();
  }
  float* Cz = C + (size_t)gz*M*ldc;
  #pragma unroll
  for (int mf = 0; mf < 4; ++mf)
    #pragma unroll
    for (int nf = 0; nf < 2; ++nf)
      #pragma unroll
      for (int j = 0; j < 4; ++j) {
        int m = gm*128 + wm*64 + mf*16 + (lane>>4)*4 + j;
        int n = gn*64 + wn*32 + nf*16 + (lane&15);
        float v = acc[mf][nf][j] + ((gz == 0) ? bias[n] : 0.f);
        if (RELU) v = fmaxf(v, 0.f);
        Cz[(size_t)m*ldc + n] = v;
      }
}

// ---------------- fused layer-2 GraphConv (single masked float4 gather) + TopK(128) + readout ----------------
__global__ __launch_bounds__(512, 4) void k_g2(
    const int* __restrict__ ei, const unsigned char* __restrict__ m1,
    const float* __restrict__ xw2, const float* __restrict__ p2,
    const float* __restrict__ x1, float* __restrict__ vbuf,
    float* __restrict__ catb)
{
  int g = blockIdx.x, tid = threadIdx.x;
  __shared__ unsigned char mk[200], mk2[200];
  __shared__ ushort eloc[1600], eidx[1600];
  __shared__ int cnt[200], off[201], wsum4[4];
  __shared__ float xw[200*XWS], sacc[200], pF[128];
  __shared__ unsigned long long keys[256];
  __shared__ float tv[200];
  __shared__ float nrm;
  if (tid < 200) { mk[tid] = m1[g*200+tid]; sacc[tid] = 0.f; mk2[tid] = 0; cnt[tid] = 0; }
  if (tid < 128) pF[tid] = p2[tid];
  for (int e = tid; e < 1600; e += 512) {
    int s = ei[g*1600 + e] - g*200;
    int d = ei[NEDGE + g*1600 + e] - g*200;
    eloc[e] = (ushort)(s | (d << 8));
  }
  if (tid < 64) {
    float a = p2[tid], b = p2[64+tid];
    float pp = a*a + b*b;
    pp += __shfl_xor(pp, 32); pp += __shfl_xor(pp, 16); pp += __shfl_xor(pp, 8);
    pp += __shfl_xor(pp, 4);  pp += __shfl_xor(pp, 2);  pp += __shfl_xor(pp, 1);
    if (tid == 0) nrm = rsqrtf(pp);
  }
  __syncthreads();
  for (int e = tid; e < 1600; e += 512) {
    int p = eloc[e];
    if (mk[p & 255] && mk[p >> 8]) atomicAdd(&cnt[p >> 8], 1);
  }
  __syncthreads();
  scan200(cnt, off, wsum4, tid);
  if (tid < 200) cnt[tid] = 0;
  __syncthreads();
  for (int e = tid; e < 1600; e += 512) {
    int p = eloc[e];
    int s = p & 255, d = p >> 8;
    if (mk[s] && mk[d]) {
      int pos = off[d] + atomicAdd(&cnt[d], 1);
      eidx[pos] = (ushort)s;
    }
  }
  // ---- single pass: v -> vbuf for m1 nodes, scores ----
  for (int hc = 0; hc < 4; ++hc) {
    int h0 = hc*32;
    __syncthreads();
    for (int i4 = tid; i4 < 1600; i4 += 512) {
      int nd = i4 >> 3, c4 = i4 & 7;
      const float4 v = *reinterpret_cast<const float4*>(xw2 + ((size_t)(g*200+nd))*256 + h0 + c4*4);
      *reinterpret_cast<float4*>(&xw[nd*XWS + c4*4]) = v;
    }
    __syncthreads();
    for (int i = tid; i < 1600; i += 512) {
      int nd = i >> 3, hp = i & 7; int h4 = hp*4, f = h0 + h4;
      if (!mk[nd]) continue;
      float4 gv = csr_gather4(eidx, xw, off[nd], off[nd+1], h4);
      float4 rt = *reinterpret_cast<const float4*>(&xw2[((size_t)(g*200+nd))*256 + 128 + f]);
      float4 v;
      v.x = fmaxf(gv.x + rt.x, 0.f);
      v.y = fmaxf(gv.y + rt.y, 0.f);
      v.z = fmaxf(gv.z + rt.z, 0.f);
      v.w = fmaxf(gv.w + rt.w, 0.f);
      *reinterpret_cast<float4*>(&vbuf[((size_t)(g*200+nd))*128 + f]) = v;
      float r = v.x*pF[f] + v.y*pF[f+1] + v.z*pF[f+2] + v.w*pF[f+3];
      r += __shfl_xor(r, 4); r += __shfl_xor(r, 2); r += __shfl_xor(r, 1);
      if ((tid & 7) == 0) sacc[nd] += r;
    }
  }
  __syncthreads();
  if (tid < 256) {
    unsigned long long kk;
    if (tid < 200) {
      float sc = mk[tid] ? sacc[tid] : -__builtin_inff();
      kk = score_key(sc, tid);
    } else kk = ~0ull;
    keys[tid] = kk;
  }
  bitonic256(keys, tid);
  if (tid < 128) mk2[(int)(keys[tid] & 0xFFFFFFFFu)] = 1;
  if (tid < 200) tv[tid] = tanhf(sacc[tid]*nrm);
  __syncthreads();
  // ---- pass 2: masked re-read + readout ----
  int fp = tid & 63, wv = tid >> 6;
  float2 mx = make_float2(-1e30f, -1e30f), sm = make_float2(0.f, 0.f);
  for (int nd = wv; nd < 200; nd += 8) {
    if (!mk2[nd]) continue;
    float2 v = *reinterpret_cast<const float2*>(&vbuf[((size_t)(g*200+nd))*128 + fp*2]);
    float t = tv[nd];
    v.x *= t; v.y *= t;
    mx.x = fmaxf(mx.x, v.x); mx.y = fmaxf(mx.y, v.y);
    sm.x += v.x; sm.y += v.y;
  }
  float2* redm = reinterpret_cast<float2*>(xw);
  float2* reds = reinterpret_cast<float2*>(xw + 1024);
  redm[fp*8 + wv] = mx;
  reds[fp*8 + wv] = sm;
  __syncthreads();
  if (tid < 64) {
    float2 m2 = make_float2(-1e30f, -1e30f), s2 = make_float2(0.f, 0.f);
    #pragma unroll
    for (int w = 0; w < 8; ++w) {
      float2 a = redm[tid*8+w], b = reds[tid*8+w];
      m2.x = fmaxf(m2.x, a.x); m2.y = fmaxf(m2.y, a.y);
      s2.x += b.x; s2.y += b.y;
    }
    catb[(size_t)g*4864 + tid*2]           = x1[g*256 + tid*2] + m2.x;
    catb[(size_t)g*4864 + tid*2 + 1]       = x1[g*256 + tid*2 + 1] + m2.y;
    catb[(size_t)g*4864 + 128 + tid*2]     = x1[g*256 + 128 + tid*2] + s2.x*(1.f/128.f);
    catb[(size_t)g*4864 + 128 + tid*2 + 1] = x1[g*256 + 128 + tid*2 + 1] + s2.y*(1.f/128.f);
  }
}

// ---------------- transpose tgt[b][ci][t] -> tgtT[(b*101+t)][128] (ci-major, zero-padded) ----------------
__global__ __launch_bounds__(256) void k_transp(
    const float* __restrict__ tgt, float* __restrict__ tgtT)
{
  int b = blockIdx.x, tid = threadIdx.x;
  __shared__ float tgs[8484];
  for (int i = tid; i < 8484; i += 256) tgs[i] = tgt[(size_t)b*8484 + i];
  __syncthreads();
  for (int i = tid; i < 12928; i += 256) {   // 101*128
    int t = i >> 7, ci = i & 127;
    tgtT[((size_t)(b*101 + t))*128 + ci] = (ci < 84) ? tgs[ci*101 + t] : 0.f;
  }
}

// ---------------- avgpool5 over conv output rows: xl[(b*101+t)][o] -> xp[(tp*512+b)][o] ----------------
__global__ __launch_bounds__(512) void k_avgpool(
    const float* __restrict__ xl, float* __restrict__ xp)
{
  int b = blockIdx.x, tid = threadIdx.x;
  for (int i = tid; i < 2432; i += 512) {    // 19*128
    int tp = i >> 7, o = i & 127;
    int t0 = tp*5;
    float s = 0.f;
    #pragma unroll
    for (int q = 0; q < 5; ++q)
      s += xl[((size_t)(b*101 + t0 + q))*128 + o];
    xp[((size_t)(tp*512 + b))*128 + o] = s*0.2f;
  }
}

// ---------------- bidirectional GRU: 768 threads = 360 cols x 2 k-halves ----------------
// Best-measured GRU structure (67us): [k][360] weight layout keeps the (always-sunk)
// per-step weight stream perfectly wave-coalesced. Partials combined in LDS.
// Structural floor: 9 structures measured (R15-R26), all alternatives regressed or failed.
__global__ __launch_bounds__(768, 3) void k_gru(
    const float* __restrict__ whht, const float* __restrict__ bhf,
    const float* __restrict__ bhb, const float* __restrict__ gi,
    float* __restrict__ catb)
{
  int blk = blockIdx.x;            // 512 blocks
  int dir = blk & 1, grp = blk >> 1;   // rows grp*2, grp*2+1
  const float* wh = whht + dir*43200;  // [k][360]
  const float* bhh = dir ? bhb : bhf;
  __shared__ float h_l[240];    // [2][120]
  __shared__ float ps[4][360];  // [row*2+kh][c] partials
  __shared__ float bhs[360];
  int tid = threadIdx.x;
  int ct = (tid < 720) ? tid : 719;
  int c  = (ct < 360) ? ct : ct - 360;   // output column 0..359
  int kh = (ct < 360) ? 0 : 1;           // k half
  float4 w4r[15];
  #pragma unroll
  for (int k = 0; k < 15; ++k) {
    int kb = kh*60 + k*4;
    w4r[k].x = wh[(kb+0)*360 + c];
    w4r[k].y = wh[(kb+1)*360 + c];
    w4r[k].z = wh[(kb+2)*360 + c];
    w4r[k].w = wh[(kb+3)*360 + c];
  }
  if (tid < 360) bhs[tid] = bhh[tid];
  if (tid < 240) h_l[tid] = 0.f;
  __syncthreads();
  for (int step = 0; step < 19; ++step) {
    int time = dir ? (18 - step) : step;
    {
      float a0 = 0.f, a1 = 0.f;
      const float4* h40 = reinterpret_cast<const float4*>(&h_l[0]);
      const float4* h41 = reinterpret_cast<const float4*>(&h_l[120]);
      #pragma unroll
      for (int k = 0; k < 15; ++k) {
        float4 w = w4r[k];
        float4 v0 = h40[kh*15 + k];
        float4 v1 = h41[kh*15 + k];
        a0 += v0.x*w.x + v0.y*w.y + v0.z*w.z + v0.w*w.w;
        a1 += v1.x*w.x + v1.y*w.y + v1.z*w.z + v1.w*w.w;
      }
      if (tid < 720) { ps[kh][c] = a0; ps[2+kh][c] = a1; }
    }
    __syncthreads();
    if (tid < 240) {
      int b2 = tid >= 120, cc = tid - b2*120;
      size_t row = (size_t)time*512 + grp*2 + b2;
      const float* gir = gi + row*768 + dir*360;
      int base = b2*2;
      float hr = ps[base][cc]     + ps[base+1][cc]     + bhs[cc];
      float hz = ps[base][120+cc] + ps[base+1][120+cc] + bhs[120+cc];
      float hn = ps[base][240+cc] + ps[base+1][240+cc] + bhs[240+cc];
      float ir = gir[cc], iz = gir[120+cc], inn = gir[240+cc];
      float r = 1.f/(1.f + expf(-(ir+hr)));
      float z = 1.f/(1.f + expf(-(iz+hz)));
      float n = tanhf(inn + r*hn);
      float hnew = (1.f - z)*n + z*h_l[tid];
      h_l[tid] = hnew;
      catb[((size_t)(grp*2+b2))*4864 + 256 + time*240 + dir*120 + cc] = hnew;
    }
    __syncthreads();
  }
}

// ---------------- final: parallel sum of 19 K-split partials + relu + logits + log_softmax ----------------
__global__ __launch_bounds__(128) void k_final(
    const float* __restrict__ xcp, const float* __restrict__ d3w,
    const float* __restrict__ d3b, float* __restrict__ out)
{
  int row = blockIdx.x;          // 512 blocks, one per output row
  int k = threadIdx.x;           // 128 threads, 102 active
  __shared__ float red[4];
  float l0 = 0.f, l1 = 0.f;
  if (k < 102) {
    float v = 0.f;
    #pragma unroll
    for (int z = 0; z < 19; ++z)
      v += xcp[(size_t)z*65536 + (size_t)row*128 + k];
    v = fmaxf(v, 0.f);
    l0 = v*d3w[k*2+0];
    l1 = v*d3w[k*2+1];
  }
  #pragma unroll
  for (int d = 32; d > 0; d >>= 1) {
    l0 += __shfl_xor(l0, d);
    l1 += __shfl_xor(l1, d);
  }
  int lane = k & 63, wv = k >> 6;
  if (lane == 0) { red[wv*2] = l0; red[wv*2+1] = l1; }
  __syncthreads();
  if (k == 0) {
    float a0 = red[0] + red[2] + d3b[0];
    float a1 = red[1] + red[3] + d3b[1];
    float m = fmaxf(a0, a1);
    float lse = m + logf(expf(a0-m) + expf(a1-m));
    out[row*2+0] = a0 - lse;
    out[row*2+1] = a1 - lse;
  }
}

extern "C" void kernel_launch(void* const* d_in, const int* in_sizes, int n_in,
                              void* d_out, int out_size, void* d_ws, size_t ws_size,
                              hipStream_t stream) {
  (void)in_sizes; (void)n_in; (void)out_size;
  const float* x      = (const float*)d_in[0];
  const int*   ei     = (const int*)d_in[1];
  const float* tgt    = (const float*)d_in[3];
  const float* w1rel  = (const float*)d_in[4];
  const float* w1root = (const float*)d_in[5];
  const float* b1     = (const float*)d_in[6];
  const float* p1     = (const float*)d_in[7];
  const float* w2rel  = (const float*)d_in[8];
  const float* w2root = (const float*)d_in[9];
  const float* b2     = (const float*)d_in[10];
  const float* p2     = (const float*)d_in[11];
  const float* cw     = (const float*)d_in[12];
  const float* cb     = (const float*)d_in[13];
  const float* wif    = (const float*)d_in[14];
  const float* whf    = (const float*)d_in[15];
  const float* bif    = (const float*)d_in[16];
  const float* bhf    = (const float*)d_in[17];
  const float* wib    = (const float*)d_in[18];
  const float* whb    = (const float*)d_in[19];
  const float* bib    = (const float*)d_in[20];
  const float* bhb    = (const float*)d_in[21];
  const float* d1w    = (const float*)d_in[22];
  const float* d1b    = (const float*)d_in[23];
  const float* d3w    = (const float*)d_in[24];
  const float* d3b    = (const float*)d_in[25];
  float* out = (float*)d_out;

  char* ws = (char*)d_ws;
  size_t off = 0;
  auto alloc = [&](size_t bytes) -> char* {
    char* p = ws + off;
    off = (off + bytes + 255) & ~(size_t)255;
    return p;
  };
  float* hin    = (float*)alloc((size_t)NNODE*128*4);     // 52.4MB (also reused as vbuf by k_g2)
  unsigned char* m1b = (unsigned char*)alloc(NNODE);
  float* tvg    = (float*)alloc((size_t)NNODE*4);         // per-node gate
  float* x1     = (float*)alloc((size_t)512*256*4);
  float* w2t    = (float*)alloc((size_t)32768*4);
  float* bias2  = (float*)alloc((size_t)256*4);
  float* xw2    = (float*)alloc((size_t)NNODE*256*4);     // 104.9MB; dead after k_g2 -> reused as tgtT + xl
  float* xp     = (float*)alloc((size_t)SEQM*128*4);      // 5.0MB
  float* wift   = (float*)alloc((size_t)98304*4);
  float* biasif = (float*)alloc((size_t)768*4);
  float* gi     = (float*)alloc((size_t)SEQM*768*4);      // 29.9MB
  float* whht   = (float*)alloc((size_t)86400*4);
  float* catb   = (float*)alloc((size_t)512*4864*4);      // 10.0MB
  float* d1wt   = (float*)alloc((size_t)622592*4);        // 2.5MB
  float* biasd1 = (float*)alloc((size_t)128*4);
  float* xcp    = (float*)alloc((size_t)19*512*128*4);    // 5.0MB
  float* Btw    = (float*)alloc((size_t)128*384*4);       // 0.2MB conv weights [o][3*128]
  if (off > ws_size) return;  // workspace too small; bail (output stays poisoned)

  // aliases into dead xw2 (valid only after k_g2):
  float* tgtT = xw2;                               // CONVROWS x 128 = 26.5MB
  float* xl   = xw2 + (size_t)CONVROWS*128;        // CONVM x 128 = 26.5MB

  k_setup<<<1024, 256, 0, stream>>>(w2rel, w2root, b2, wif, wib, bif, bib,
                                    whf, whb, d1w, d1b, cw,
                                    w2t, bias2, wift, biasif, whht, d1wt, biasd1, catb, Btw);
  k_g1<<<512, 512, 0, stream>>>(x, ei, w1rel, w1root, b1, p1, hin, m1b, tvg, x1);
  k_gemm32<0,0,1><<<dim3(4,800,1), 256, 0, stream>>>(hin, w2t, bias2, tvg, xw2, NNODE, 128, 256);
  k_g2<<<512, 512, 0, stream>>>(ei, m1b, xw2, p2, x1, hin, catb);
  k_transp<<<512, 256, 0, stream>>>(tgt, tgtT);
  k_gemm32<1,1,0><<<dim3(2,404,1), 256, 0, stream>>>(tgtT, Btw, cb, nullptr, xl, CONVM, 384, 128);
  k_avgpool<<<512, 512, 0, stream>>>(xl, xp);
  k_gemm32<0,0,0><<<dim3(12,76,1), 256, 0, stream>>>(xp, wift, biasif, nullptr, gi, SEQM, 128, 768);
  k_gru<<<512, 768, 0, stream>>>(whht, bhf, bhb, gi, catb);
  k_gemm32<0,0,0><<<dim3(2,4,19), 256, 0, stream>>>(catb, d1wt, biasd1, nullptr, xcp, 512, 4864, 128);
  k_final<<<512, 128, 0, stream>>>(xcp, d3w, d3b, out);
}